// Round 13
// baseline (144.640 us; speedup 1.0000x reference)
//
#include <hip/hip_runtime.h>

#define B 256
#define EPSV 1e-5f

// ---------- output offsets (f32 elements) ----------
#define OFF_ASSIGN 0
#define OFF_LOSS   256
#define OFF_ACT4   257
#define OFF_L1     2817
#define OFF_L2     12847873
#define OFF_L3     14486273

__device__ __forceinline__ void wave_reduce2(float& s, float& q) {
#pragma unroll
    for (int o = 32; o > 0; o >>= 1) {
        s += __shfl_down(s, o, 64);
        q += __shfl_down(q, o, 64);
    }
}

// K1: conv1 (blocks 0..1535) + w1/k3s transpose (blocks 1536..1963)
__global__ __launch_bounds__(256) void conv1_kernel(
        const float* __restrict__ inp, const float* __restrict__ w,
        const float* __restrict__ bias, float* __restrict__ c1,
        float* __restrict__ part,
        const float* __restrict__ w1, const float* __restrict__ k3,
        float* __restrict__ w1t, float* __restrict__ k3st) {
    int bc = blockIdx.x;
    int tid = threadIdx.x;
    if (bc >= 1536) {
        int idx = (bc - 1536) * 256 + tid;
        if (idx < 48000) {
            int c = idx / 120, o = idx % 120;
            w1t[idx] = w1[o * 400 + c];
        } else if (idx < 48000 + 61440) {
            int j = idx - 48000;
            int c = j >> 9, k = j & 511;
            k3st[j] = k3[k * 120 + c];
        }
        return;
    }
    int b = bc / 6, c = bc % 6;
    __shared__ float ws[75];
    __shared__ float rs[4], rq[4];
    if (tid < 75) ws[tid] = w[c * 75 + tid];
    __syncthreads();
    const float* ip = inp + b * 3072;
    float bs = bias[c];
    float s = 0.f, sq = 0.f;
    for (int hw = tid; hw < 784; hw += 256) {
        int oh = hw / 28, ow = hw % 28;
        float acc = bs;
#pragma unroll
        for (int ic = 0; ic < 3; ++ic) {
            const float* ipc = ip + ic * 1024 + oh * 32 + ow;
            const float* wc = ws + ic * 25;
#pragma unroll
            for (int kh = 0; kh < 5; ++kh)
#pragma unroll
                for (int kw = 0; kw < 5; ++kw)
                    acc += ipc[kh * 32 + kw] * wc[kh * 5 + kw];
        }
        c1[bc * 784 + hw] = acc;
        s += acc; sq += acc * acc;
    }
    wave_reduce2(s, sq);
    if ((tid & 63) == 0) { rs[tid >> 6] = s; rq[tid >> 6] = sq; }
    __syncthreads();
    if (tid == 0) {
        part[bc * 2]     = rs[0] + rs[1] + rs[2] + rs[3];
        part[bc * 2 + 1] = rq[0] + rq[1] + rq[2] + rq[3];
    }
}

// K2: block (b, h=0..3): redundant stats1 + BN act1 -> LDS + 16 logits1 keys.
// h==0 additionally: pool -> conv2 -> c2raw + part2. 4 blocks/CU.
__global__ __launch_bounds__(512) void stage1_kernel(
        const float* __restrict__ c1raw, const float* __restrict__ part1,
        const float* __restrict__ g1, const float* __restrict__ bb1,
        const float* __restrict__ k1s,
        const float* __restrict__ c2w, const float* __restrict__ c2b,
        float* __restrict__ out, float* __restrict__ c2raw,
        float* __restrict__ part2) {
    int b = blockIdx.x >> 2, h = blockIdx.x & 3;
    int tid = threadIdx.x;
    int lane = tid & 63, wid = tid >> 6;     // 8 waves
    __shared__ __align__(16) float act[4704];
    __shared__ float sk1[384], k2sq1[64];
    __shared__ float chs[6], chq[6], ssc[6], ssh[6];
    __shared__ float xp[1176];
    __shared__ float w2s[2400];
    if (tid < 384) sk1[tid] = k1s[tid];
    if (h == 0) for (int i = tid; i < 2400; i += 512) w2s[i] = c2w[i];
    __syncthreads();
    if (wid < 6) {                            // stats1: wave = channel
        float s = 0.f, q = 0.f;
#pragma unroll
        for (int j = 0; j < 4; ++j) {
            int bi = lane + 64 * j;
            s += part1[(bi * 6 + wid) * 2];
            q += part1[(bi * 6 + wid) * 2 + 1];
        }
        wave_reduce2(s, q);
        if (lane == 0) { chs[wid] = s; chq[wid] = q; }
    }
    if (tid >= 384 && tid < 448) {            // K2 norms (wave 6)
        int k = tid - 384;
        float s = 0.f;
#pragma unroll
        for (int c = 0; c < 6; ++c) { float x = sk1[k * 6 + c]; s += x * x; }
        k2sq1[k] = s;
    }
    __syncthreads();
    if (tid < 6) {
        float m = chs[tid] * (1.f / 200704.f);
        float v = chq[tid] * (1.f / 200704.f) - m * m;
        float sc = g1[tid] * rsqrtf(v + EPSV);
        ssc[tid] = sc; ssh[tid] = bb1[tid] - m * sc;
    }
    __syncthreads();
    for (int i = tid; i < 4704; i += 512) {
        int c = i / 784;
        act[i] = c1raw[b * 4704 + i] * ssc[c] + ssh[c];
    }
    __syncthreads();
    // logits1: 16 keys [h*16, h*16+16), dot form
    for (int hw = tid; hw < 784; hw += 512) {
        float a0 = act[hw], a1 = act[784 + hw], a2 = act[1568 + hw];
        float a3 = act[2352 + hw], a4 = act[3136 + hw], a5 = act[3920 + hw];
        float A2 = a0*a0 + a1*a1 + a2*a2 + a3*a3 + a4*a4 + a5*a5;
        float* op = out + OFF_L1 + (long)b * 50176 + (h * 16) * 784 + hw;
#pragma unroll
        for (int kk = 0; kk < 16; ++kk) {
            int k = h * 16 + kk;
            const float* kp = sk1 + k * 6;
            float dot = a0*kp[0] + a1*kp[1] + a2*kp[2] + a3*kp[3] + a4*kp[4] + a5*kp[5];
            op[kk * 784] = -sqrtf(fmaxf(A2 + k2sq1[k] - 2.f * dot, 0.f));
        }
    }
    if (h != 0) return;
    __syncthreads();
    for (int i = tid; i < 1176; i += 512) {   // pool -> xp (LDS)
        int c = i / 196, p = i % 196, ph = p / 14, pw = p % 14;
        const float* ap = act + c * 784 + ph * 56 + pw * 2;
        float m = fmaxf(fmaxf(ap[0], ap[1]), fmaxf(ap[28], ap[29]));
        xp[i] = fmaxf(m, 0.f);
    }
    __syncthreads();
    float* sa = act;                          // alias: act dead now
    for (int i = tid; i < 1600; i += 512) {   // conv2
        int c = i / 100, hw = i - c * 100;
        int oh = hw / 10, ow = hw - oh * 10;
        float acc = c2b[c];
#pragma unroll
        for (int ic = 0; ic < 6; ++ic) {
            const float* xsrc = xp + ic * 196 + oh * 14 + ow;
            const float* wp = w2s + c * 150 + ic * 25;
#pragma unroll
            for (int kh = 0; kh < 5; ++kh)
#pragma unroll
                for (int kw = 0; kw < 5; ++kw)
                    acc += xsrc[kh * 14 + kw] * wp[kh * 5 + kw];
        }
        sa[i] = acc;
        c2raw[b * 1600 + i] = acc;
    }
    __syncthreads();
#pragma unroll
    for (int r = 0; r < 2; ++r) {             // partials: wave handles ch 2w, 2w+1
        int cc = wid * 2 + r;
        float s = 0.f, q = 0.f;
        if (lane < 100) { float x = sa[cc * 100 + lane]; s = x; q = x * x; }
        if (lane < 36)  { float x = sa[cc * 100 + 64 + lane]; s += x; q += x * x; }
        wave_reduce2(s, q);
        if (lane == 0) { part2[(b * 16 + cc) * 2] = s; part2[(b * 16 + cc) * 2 + 1] = q; }
    }
}

// K3: block (b, h=0..2): redundant stats2 + BN act2 -> LDS.
// h==1/2: 32 logits2 keys each. h==0: pool + fc1 + logits3 + act4 + rank-NG.
__global__ __launch_bounds__(512) void stage2_kernel(
        const float* __restrict__ c2raw, const float* __restrict__ part2,
        const float* __restrict__ g2, const float* __restrict__ bb2,
        const float* __restrict__ k2s,
        const float* __restrict__ w1t, const float* __restrict__ f1b,
        const float* __restrict__ f2w, const float* __restrict__ f2b,
        const float* __restrict__ k3st,
        float* __restrict__ out, float* __restrict__ lossb) {
    int bh = blockIdx.x;
    int b = bh / 3, h = bh - b * 3;
    int tid = threadIdx.x;
    int lane = tid & 63, wid = tid >> 6;     // 8 waves
    __shared__ __align__(16) float sa[1600];
    __shared__ float sk2[1024], k2sq2[64], A2s[112];
    __shared__ float chs[16], chq[16], ssc[16], ssh[16];
    __shared__ float xs[400];
    __shared__ float partq[512];
    __shared__ float a3r[120], a3p[120];
    __shared__ __align__(16) float sv[512];
    __shared__ float wsum[8], wmv[8];
    __shared__ int wmi[8];
    sk2[tid] = k2s[tid];
    sk2[tid + 512] = k2s[tid + 512];
    {   // stats2: wave w -> channels w and w+8
#pragma unroll
        for (int r = 0; r < 2; ++r) {
            int ch = wid + r * 8;
            float s = 0.f, q = 0.f;
#pragma unroll
            for (int j = 0; j < 4; ++j) {
                int bi = lane + 64 * j;
                s += part2[(bi * 16 + ch) * 2];
                q += part2[(bi * 16 + ch) * 2 + 1];
            }
            wave_reduce2(s, q);
            if (lane == 0) { chs[ch] = s; chq[ch] = q; }
        }
    }
    __syncthreads();
    if (tid < 16) {
        float m = chs[tid] * (1.f / 25600.f);
        float v = chq[tid] * (1.f / 25600.f) - m * m;
        float sc = g2[tid] * rsqrtf(v + EPSV);
        ssc[tid] = sc; ssh[tid] = bb2[tid] - m * sc;
    }
    if (tid >= 64 && tid < 128) {             // key norms
        int k = tid - 64;
        float s = 0.f;
#pragma unroll
        for (int c = 0; c < 16; ++c) { float x = sk2[k * 16 + c]; s += x * x; }
        k2sq2[k] = s;
    }
    __syncthreads();
    for (int i = tid; i < 1600; i += 512) {
        int c = i / 100;
        sa[i] = c2raw[b * 1600 + i] * ssc[c] + ssh[c];
    }
    __syncthreads();
    if (tid < 100) {                          // activation norms
        float s = 0.f;
#pragma unroll
        for (int c = 0; c < 16; ++c) { float a = sa[c * 100 + tid]; s += a * a; }
        A2s[tid] = s;
    }
    __syncthreads();
    if (h != 0) {                             // logits2: 32 keys
        int kb = (h - 1) * 32;
        for (int i = tid; i < 3200; i += 512) {
            int kk = i / 100, hw = i - kk * 100;
            int k = kb + kk;
            const float* kp = sk2 + k * 16;
            float dot = 0.f;
#pragma unroll
            for (int c = 0; c < 16; ++c) dot += sa[c * 100 + hw] * kp[c];
            out[OFF_L2 + (long)b * 6400 + k * 100 + hw] =
                -sqrtf(fmaxf(A2s[hw] + k2sq2[k] - 2.f * dot, 0.f));
        }
        return;
    }
    // ---------------- head (h == 0) ----------------
    for (int i = tid; i < 400; i += 512) {    // pool -> xs
        int c = i / 25, p = i % 25, ph = p / 5, pw = p % 5;
        const float* ap = sa + c * 100 + ph * 20 + pw * 2;
        float m = fmaxf(fmaxf(ap[0], ap[1]), fmaxf(ap[10], ap[11]));
        xs[i] = fmaxf(m, 0.f);
    }
    __syncthreads();
    {   // fc1: 4-way K-split, coalesced w1t columns
        int o = tid & 127, q4 = tid >> 7;
        float s = 0.f;
        if (o < 120) {
            const float* wp = w1t + (q4 * 100) * 120 + o;
            const float* xq = xs + q4 * 100;
#pragma unroll 10
            for (int c = 0; c < 100; ++c) s += xq[c] * wp[c * 120];
        }
        partq[q4 * 128 + o] = s;
    }
    __syncthreads();
    if (tid < 120) {
        float acc = f1b[tid] + partq[tid] + partq[128 + tid] + partq[256 + tid] + partq[384 + tid];
        a3r[tid] = acc;
        a3p[tid] = fmaxf(acc, 0.f);
    }
    __syncthreads();
    float v;
    {   // logits3: thread = key, coalesced k3st columns
        const float* kp = k3st + tid;
        float s = 0.f;
#pragma unroll 8
        for (int c = 0; c < 120; ++c) { float d = a3r[c] - kp[c * 512]; s += d * d; }
        v = -sqrtf(s);
        sv[tid] = v;
        out[OFF_L3 + (long)b * 512 + tid] = v;
    }
    if (tid < 10) {
        float acc = f2b[tid];
        const float* wp = f2w + tid * 120;
#pragma unroll 8
        for (int c = 0; c < 120; ++c) acc += a3p[c] * wp[c];
        out[OFF_ACT4 + b * 10 + tid] = acc;
    }
    __syncthreads();
    // rank(value) == sorted position; sum v^2 exp(-rank)
    const float4* sv4 = reinterpret_cast<const float4*>(sv);
    int cnt = 0;
#pragma unroll 8
    for (int j4 = 0; j4 < 128; ++j4) {
        float4 o4 = sv4[j4];
        int jb = j4 * 4;
        cnt += (o4.x < v || (o4.x == v && jb < tid)) ? 1 : 0;
        cnt += (o4.y < v || (o4.y == v && jb + 1 < tid)) ? 1 : 0;
        cnt += (o4.z < v || (o4.z == v && jb + 2 < tid)) ? 1 : 0;
        cnt += (o4.w < v || (o4.w == v && jb + 3 < tid)) ? 1 : 0;
    }
    float contrib = v * v * expf(-(float)cnt);
    float ssum = contrib;
#pragma unroll
    for (int o = 32; o > 0; o >>= 1) ssum += __shfl_down(ssum, o, 64);
    float mv = v; int mi = tid;
#pragma unroll
    for (int o = 32; o > 0; o >>= 1) {
        float ov = __shfl_down(mv, o, 64);
        int oi = __shfl_down(mi, o, 64);
        if (ov > mv || (ov == mv && oi < mi)) { mv = ov; mi = oi; }
    }
    if (lane == 0) { wsum[wid] = ssum; wmv[wid] = mv; wmi[wid] = mi; }
    __syncthreads();
    if (tid == 0) {
        float tot = 0.f;
        float bmv = wmv[0]; int bmi = wmi[0];
#pragma unroll
        for (int w = 0; w < 8; ++w) {
            tot += wsum[w];
            if (wmv[w] > bmv || (wmv[w] == bmv && wmi[w] < bmi)) { bmv = wmv[w]; bmi = wmi[w]; }
        }
        lossb[b] = tot;
        out[OFF_ASSIGN + b] = (float)bmi;
    }
}

__global__ void final_kernel(const float* __restrict__ loss_b, float* __restrict__ out_loss) {
    __shared__ float r[256];
    int tid = threadIdx.x;
    r[tid] = loss_b[tid];
    __syncthreads();
    for (int s = 128; s > 0; s >>= 1) {
        if (tid < s) r[tid] += r[tid + s];
        __syncthreads();
    }
    if (tid == 0) out_loss[0] = r[0] / 256.f;
}

extern "C" void kernel_launch(void* const* d_in, const int* in_sizes, int n_in,
                              void* d_out, int out_size, void* d_ws, size_t ws_size,
                              hipStream_t stream) {
    const float* inp = (const float*)d_in[0];
    const float* c1w = (const float*)d_in[1];
    const float* c1b = (const float*)d_in[2];
    const float* g1  = (const float*)d_in[3];
    const float* bb1 = (const float*)d_in[4];
    const float* c2w = (const float*)d_in[5];
    const float* c2b = (const float*)d_in[6];
    const float* g2  = (const float*)d_in[7];
    const float* bb2 = (const float*)d_in[8];
    const float* f1w = (const float*)d_in[9];
    const float* f1b = (const float*)d_in[10];
    const float* f2w = (const float*)d_in[11];
    const float* f2b = (const float*)d_in[12];
    const float* k1  = (const float*)d_in[13];
    const float* k2  = (const float*)d_in[14];
    const float* k3  = (const float*)d_in[15];
    float* out = (float*)d_out;

    float* W = (float*)d_ws;
    float* c1raw = W;                   // 1204224
    float* part1 = c1raw + 1204224;     // 3072
    float* c2raw = part1 + 3072;        // 409600
    float* part2 = c2raw + 409600;      // 8192
    float* lossb = part2 + 8192;        // 256
    float* w1t   = lossb + 256;         // 48000
    float* k3st  = w1t + 48000;         // 61440

    conv1_kernel<<<1964, 256, 0, stream>>>(inp, c1w, c1b, c1raw, part1,
                                           f1w, k3, w1t, k3st);
    stage1_kernel<<<B * 4, 512, 0, stream>>>(c1raw, part1, g1, bb1, k1, c2w, c2b,
                                             out, c2raw, part2);
    stage2_kernel<<<B * 3, 512, 0, stream>>>(c2raw, part2, g2, bb2, k2,
                                             w1t, f1b, f2w, f2b, k3st, out, lossb);
    final_kernel<<<1, 256, 0, stream>>>(lossb, out + OFF_LOSS);
}

// Round 14
// 91.789 us; speedup vs baseline: 1.5758x; 1.5758x over previous
//
#include <hip/hip_runtime.h>

#define B 256
#define EPSV 1e-5f

// ---------- output offsets (f32 elements) ----------
#define OFF_ASSIGN 0
#define OFF_LOSS   256
#define OFF_ACT4   257
#define OFF_L1     2817
#define OFF_L2     12847873
#define OFF_L3     14486273

__device__ __forceinline__ void wave_reduce2(float& s, float& q) {
#pragma unroll
    for (int o = 32; o > 0; o >>= 1) {
        s += __shfl_down(s, o, 64);
        q += __shfl_down(q, o, 64);
    }
}

// K1: conv1 (blocks 0..1535) + w1/k3s transpose (blocks 1536..1963)
__global__ __launch_bounds__(256) void conv1_kernel(
        const float* __restrict__ inp, const float* __restrict__ w,
        const float* __restrict__ bias, float* __restrict__ c1,
        float* __restrict__ part,
        const float* __restrict__ w1, const float* __restrict__ k3,
        float* __restrict__ w1t, float* __restrict__ k3st) {
    int bc = blockIdx.x;
    int tid = threadIdx.x;
    if (bc >= 1536) {
        int idx = (bc - 1536) * 256 + tid;
        if (idx < 48000) {
            int c = idx / 120, o = idx % 120;
            w1t[idx] = w1[o * 400 + c];
        } else if (idx < 48000 + 61440) {
            int j = idx - 48000;
            int c = j >> 9, k = j & 511;
            k3st[j] = k3[k * 120 + c];
        }
        return;
    }
    int b = bc / 6, c = bc % 6;
    __shared__ float ws[75];
    __shared__ float rs[4], rq[4];
    if (tid < 75) ws[tid] = w[c * 75 + tid];
    __syncthreads();
    const float* ip = inp + b * 3072;
    float bs = bias[c];
    float s = 0.f, sq = 0.f;
    for (int hw = tid; hw < 784; hw += 256) {
        int oh = hw / 28, ow = hw % 28;
        float acc = bs;
#pragma unroll
        for (int ic = 0; ic < 3; ++ic) {
            const float* ipc = ip + ic * 1024 + oh * 32 + ow;
            const float* wc = ws + ic * 25;
#pragma unroll
            for (int kh = 0; kh < 5; ++kh)
#pragma unroll
                for (int kw = 0; kw < 5; ++kw)
                    acc += ipc[kh * 32 + kw] * wc[kh * 5 + kw];
        }
        c1[bc * 784 + hw] = acc;
        s += acc; sq += acc * acc;
    }
    wave_reduce2(s, sq);
    if ((tid & 63) == 0) { rs[tid >> 6] = s; rq[tid >> 6] = sq; }
    __syncthreads();
    if (tid == 0) {
        part[bc * 2]     = rs[0] + rs[1] + rs[2] + rs[3];
        part[bc * 2 + 1] = rq[0] + rq[1] + rq[2] + rq[3];
    }
}

// K2: one block per b, 1024 thr (16 waves): redundant stats1 + BN -> LDS +
// logits1 (dot-form, k-outer, 784 thr) || pool (240 thr) + conv2 + partials.
__global__ __launch_bounds__(1024) void stage1_kernel(
        const float* __restrict__ c1raw, const float* __restrict__ part1,
        const float* __restrict__ g1, const float* __restrict__ bb1,
        const float* __restrict__ k1s,
        const float* __restrict__ c2w, const float* __restrict__ c2b,
        float* __restrict__ out, float* __restrict__ c2raw,
        float* __restrict__ part2) {
    int b = blockIdx.x, tid = threadIdx.x;
    int lane = tid & 63, wid = tid >> 6;     // 16 waves
    __shared__ __align__(16) float act[4704];
    __shared__ float sk1[384], k2sq1[64];
    __shared__ float w2s[2400];
    __shared__ float xp[1176];
    __shared__ __align__(16) float sa[1600];
    __shared__ float chs[6], chq[6], ssc[6], ssh[6];
    if (wid < 6) {                            // stats1: wave = channel (global reads)
        float s = 0.f, q = 0.f;
#pragma unroll
        for (int j = 0; j < 4; ++j) {
            int bi = lane + 64 * j;
            s += part1[(bi * 6 + wid) * 2];
            q += part1[(bi * 6 + wid) * 2 + 1];
        }
        wave_reduce2(s, q);
        if (lane == 0) { chs[wid] = s; chq[wid] = q; }
    }
    if (tid >= 640 && tid < 1024) sk1[tid - 640] = k1s[tid - 640];  // waves 10-15 load keys
    for (int i = tid; i < 2400; i += 1024) w2s[i] = c2w[i];
    __syncthreads();
    if (tid < 6) {
        float m = chs[tid] * (1.f / 200704.f);
        float v = chq[tid] * (1.f / 200704.f) - m * m;
        float sc = g1[tid] * rsqrtf(v + EPSV);
        ssc[tid] = sc; ssh[tid] = bb1[tid] - m * sc;
    }
    if (tid >= 64 && tid < 128) {             // key norms
        int k = tid - 64;
        float s = 0.f;
#pragma unroll
        for (int c = 0; c < 6; ++c) { float x = sk1[k * 6 + c]; s += x * x; }
        k2sq1[k] = s;
    }
    __syncthreads();
    for (int i = tid; i < 4704; i += 1024) {  // BN from global c1raw
        int c = i / 784;
        act[i] = c1raw[b * 4704 + i] * ssc[c] + ssh[c];
    }
    __syncthreads();
    if (tid < 784) {                          // logits1: act in regs, k-outer, dot form
        float a0 = act[tid], a1 = act[784 + tid], a2 = act[1568 + tid];
        float a3 = act[2352 + tid], a4 = act[3136 + tid], a5 = act[3920 + tid];
        float A2 = a0*a0 + a1*a1 + a2*a2 + a3*a3 + a4*a4 + a5*a5;
        float* op = out + OFF_L1 + (long)b * 50176 + tid;
#pragma unroll 4
        for (int k = 0; k < 64; ++k) {
            const float* kp = sk1 + k * 6;
            float dot = a0*kp[0] + a1*kp[1] + a2*kp[2] + a3*kp[3] + a4*kp[4] + a5*kp[5];
            *op = -sqrtf(fmaxf(A2 + k2sq1[k] - 2.f * dot, 0.f));
            op += 784;
        }
    } else {                                  // pool on spare threads
        for (int i = tid - 784; i < 1176; i += 240) {
            int c = i / 196, p = i % 196, ph = p / 14, pw = p % 14;
            const float* ap = act + c * 784 + ph * 56 + pw * 2;
            float m = fmaxf(fmaxf(ap[0], ap[1]), fmaxf(ap[28], ap[29]));
            xp[i] = fmaxf(m, 0.f);
        }
    }
    __syncthreads();
    for (int i = tid; i < 1600; i += 1024) {  // conv2
        int c = i / 100, hw = i - c * 100;
        int oh = hw / 10, ow = hw - oh * 10;
        float acc = c2b[c];
#pragma unroll
        for (int ic = 0; ic < 6; ++ic) {
            const float* xsrc = xp + ic * 196 + oh * 14 + ow;
            const float* wp = w2s + c * 150 + ic * 25;
#pragma unroll
            for (int kh = 0; kh < 5; ++kh)
#pragma unroll
                for (int kw = 0; kw < 5; ++kw)
                    acc += xsrc[kh * 14 + kw] * wp[kh * 5 + kw];
        }
        sa[i] = acc;
        c2raw[b * 1600 + i] = acc;
    }
    __syncthreads();
    {   // partials: wave = channel (16 waves)
        float s = 0.f, q = 0.f;
        if (lane < 100) { float x = sa[wid * 100 + lane]; s = x; q = x * x; }
        if (lane < 36)  { float x = sa[wid * 100 + 64 + lane]; s += x; q += x * x; }
        wave_reduce2(s, q);
        if (lane == 0) { part2[(b * 16 + wid) * 2] = s; part2[(b * 16 + wid) * 2 + 1] = q; }
    }
}

// K3: one block per b, 1024 thr: redundant stats2 + BN -> LDS + logits2 (800 thr)
// || pool (224 thr) + fc1 + logits3 + act4 + rank-based NG loss + argmax.
__global__ __launch_bounds__(1024) void stage2_kernel(
        const float* __restrict__ c2raw, const float* __restrict__ part2,
        const float* __restrict__ g2, const float* __restrict__ bb2,
        const float* __restrict__ k2s,
        const float* __restrict__ w1t, const float* __restrict__ f1b,
        const float* __restrict__ f2w, const float* __restrict__ f2b,
        const float* __restrict__ k3st,
        float* __restrict__ out, float* __restrict__ lossb) {
    int b = blockIdx.x, tid = threadIdx.x;
    int lane = tid & 63, wid = tid >> 6;     // 16 waves
    __shared__ __align__(16) float sa[1600];
    __shared__ float sk2[1024], k2sq2[64];
    __shared__ float chs[16], chq[16], ssc[16], ssh[16];
    __shared__ float xs[400];
    __shared__ float partq[1024];
    __shared__ float a3r[120], a3p[120];
    __shared__ __align__(16) float sv[512];
    __shared__ __align__(16) float pv[1024];
    __shared__ int cntp[1024];
    __shared__ float wsum[8], wmv[8];
    __shared__ int wmi[8];
    {   // stats2: wave = channel
        float s = 0.f, q = 0.f;
#pragma unroll
        for (int j = 0; j < 4; ++j) {
            int bi = lane + 64 * j;
            s += part2[(bi * 16 + wid) * 2];
            q += part2[(bi * 16 + wid) * 2 + 1];
        }
        wave_reduce2(s, q);
        if (lane == 0) { chs[wid] = s; chq[wid] = q; }
    }
    sk2[tid] = k2s[tid];
    __syncthreads();
    if (tid < 16) {
        float m = chs[tid] * (1.f / 25600.f);
        float v = chq[tid] * (1.f / 25600.f) - m * m;
        float sc = g2[tid] * rsqrtf(v + EPSV);
        ssc[tid] = sc; ssh[tid] = bb2[tid] - m * sc;
    }
    if (tid >= 64 && tid < 128) {             // key norms
        int k = tid - 64;
        float s = 0.f;
#pragma unroll
        for (int c = 0; c < 16; ++c) { float x = sk2[k * 16 + c]; s += x * x; }
        k2sq2[k] = s;
    }
    __syncthreads();
    for (int i = tid; i < 1600; i += 1024) {
        int c = i / 100;
        sa[i] = c2raw[b * 1600 + i] * ssc[c] + ssh[c];
    }
    __syncthreads();
    if (tid < 800) {                          // logits2: act regs, k-eighth per thread
        int kg = tid / 100, hw = tid - kg * 100;
        float a[16], A2 = 0.f;
#pragma unroll
        for (int c = 0; c < 16; ++c) { a[c] = sa[c * 100 + hw]; A2 += a[c] * a[c]; }
        float* op2 = out + OFF_L2 + (long)b * 6400 + kg * 800 + hw;
#pragma unroll
        for (int k = kg * 8; k < kg * 8 + 8; ++k) {
            const float* kp = sk2 + k * 16;
            float dot = 0.f;
#pragma unroll
            for (int c = 0; c < 16; ++c) dot += a[c] * kp[c];
            *op2 = -sqrtf(fmaxf(A2 + k2sq2[k] - 2.f * dot, 0.f));
            op2 += 100;
        }
    } else {                                  // pool on spare threads
        for (int i = tid - 800; i < 400; i += 224) {
            int c = i / 25, p = i % 25, ph = p / 5, pw = p % 5;
            const float* ap = sa + c * 100 + ph * 20 + pw * 2;
            float m = fmaxf(fmaxf(ap[0], ap[1]), fmaxf(ap[10], ap[11]));
            xs[i] = fmaxf(m, 0.f);
        }
    }
    __syncthreads();
    {   // fc1: 8-way K-split, coalesced w1t columns
        int o = tid & 127, q8 = tid >> 7;
        float s = 0.f;
        if (o < 120) {
            const float* wp = w1t + (q8 * 50) * 120 + o;
            const float* xq = xs + q8 * 50;
#pragma unroll 10
            for (int c = 0; c < 50; ++c) s += xq[c] * wp[c * 120];
        }
        partq[q8 * 128 + o] = s;
    }
    __syncthreads();
    if (tid < 120) {
        float acc = f1b[tid];
#pragma unroll
        for (int q8 = 0; q8 < 8; ++q8) acc += partq[q8 * 128 + tid];
        a3r[tid] = acc;
        a3p[tid] = fmaxf(acc, 0.f);
    }
    __syncthreads();
    {   // logits3: 2 threads per key, coalesced k3st columns
        int k = tid & 511, h = tid >> 9;
        const float* kp = k3st + k;
        float s = 0.f;
#pragma unroll 6
        for (int c = h * 60; c < h * 60 + 60; ++c) {
            float d = a3r[c] - kp[c * 512];
            s += d * d;
        }
        pv[h * 512 + k] = s;
    }
    if (tid < 10) {
        float acc = f2b[tid];
        const float* wp = f2w + tid * 120;
#pragma unroll 8
        for (int c = 0; c < 120; ++c) acc += a3p[c] * wp[c];
        out[OFF_ACT4 + b * 10 + tid] = acc;
    }
    __syncthreads();
    if (tid < 512) {
        float v = -sqrtf(pv[tid] + pv[512 + tid]);
        sv[tid] = v;
        out[OFF_L3 + (long)b * 512 + tid] = v;
    }
    __syncthreads();
    {   // rank scan: 2 threads per value
        int i = tid & 511, h = tid >> 9;
        float v = sv[i];
        const float4* sv4 = reinterpret_cast<const float4*>(sv);
        int cnt = 0;
#pragma unroll 8
        for (int j4 = h * 64; j4 < h * 64 + 64; ++j4) {
            float4 o4 = sv4[j4];
            int jb = j4 * 4;
            cnt += (o4.x < v || (o4.x == v && jb < i)) ? 1 : 0;
            cnt += (o4.y < v || (o4.y == v && jb + 1 < i)) ? 1 : 0;
            cnt += (o4.z < v || (o4.z == v && jb + 2 < i)) ? 1 : 0;
            cnt += (o4.w < v || (o4.w == v && jb + 3 < i)) ? 1 : 0;
        }
        cntp[h * 512 + i] = cnt;
    }
    __syncthreads();
    if (tid < 512) {
        float v = sv[tid];
        int cnt = cntp[tid] + cntp[512 + tid];
        float contrib = v * v * expf(-(float)cnt);
        float ssum = contrib;
#pragma unroll
        for (int o = 32; o > 0; o >>= 1) ssum += __shfl_down(ssum, o, 64);
        float mv = v; int mi = tid;
#pragma unroll
        for (int o = 32; o > 0; o >>= 1) {
            float ov = __shfl_down(mv, o, 64);
            int oi = __shfl_down(mi, o, 64);
            if (ov > mv || (ov == mv && oi < mi)) { mv = ov; mi = oi; }
        }
        if (lane == 0) { wsum[wid] = ssum; wmv[wid] = mv; wmi[wid] = mi; }
    }
    __syncthreads();
    if (tid == 0) {
        float tot = 0.f;
        float bmv = wmv[0]; int bmi = wmi[0];
#pragma unroll
        for (int w = 0; w < 8; ++w) {
            tot += wsum[w];
            if (wmv[w] > bmv || (wmv[w] == bmv && wmi[w] < bmi)) { bmv = wmv[w]; bmi = wmi[w]; }
        }
        lossb[b] = tot;
        out[OFF_ASSIGN + b] = (float)bmi;
    }
}

__global__ void final_kernel(const float* __restrict__ loss_b, float* __restrict__ out_loss) {
    __shared__ float r[256];
    int tid = threadIdx.x;
    r[tid] = loss_b[tid];
    __syncthreads();
    for (int s = 128; s > 0; s >>= 1) {
        if (tid < s) r[tid] += r[tid + s];
        __syncthreads();
    }
    if (tid == 0) out_loss[0] = r[0] / 256.f;
}

extern "C" void kernel_launch(void* const* d_in, const int* in_sizes, int n_in,
                              void* d_out, int out_size, void* d_ws, size_t ws_size,
                              hipStream_t stream) {
    const float* inp = (const float*)d_in[0];
    const float* c1w = (const float*)d_in[1];
    const float* c1b = (const float*)d_in[2];
    const float* g1  = (const float*)d_in[3];
    const float* bb1 = (const float*)d_in[4];
    const float* c2w = (const float*)d_in[5];
    const float* c2b = (const float*)d_in[6];
    const float* g2  = (const float*)d_in[7];
    const float* bb2 = (const float*)d_in[8];
    const float* f1w = (const float*)d_in[9];
    const float* f1b = (const float*)d_in[10];
    const float* f2w = (const float*)d_in[11];
    const float* f2b = (const float*)d_in[12];
    const float* k1  = (const float*)d_in[13];
    const float* k2  = (const float*)d_in[14];
    const float* k3  = (const float*)d_in[15];
    float* out = (float*)d_out;

    float* W = (float*)d_ws;
    float* c1raw = W;                   // 1204224
    float* part1 = c1raw + 1204224;     // 3072
    float* c2raw = part1 + 3072;        // 409600
    float* part2 = c2raw + 409600;      // 8192
    float* lossb = part2 + 8192;        // 256
    float* w1t   = lossb + 256;         // 48000
    float* k3st  = w1t + 48000;         // 61440

    conv1_kernel<<<1964, 256, 0, stream>>>(inp, c1w, c1b, c1raw, part1,
                                           f1w, k3, w1t, k3st);
    stage1_kernel<<<B, 1024, 0, stream>>>(c1raw, part1, g1, bb1, k1, c2w, c2b,
                                          out, c2raw, part2);
    stage2_kernel<<<B, 1024, 0, stream>>>(c2raw, part2, g2, bb2, k2,
                                          w1t, f1b, f2w, f2b, k3st, out, lossb);
    final_kernel<<<1, 256, 0, stream>>>(lossb, out + OFF_LOSS);
}